// Round 1
// baseline (357.461 us; speedup 1.0000x reference)
//
#include <hip/hip_runtime.h>
#include <hip/hip_bf16.h>

#define BLOCK 32
#define HO 128
#define WO 128
#define NTOK 8192
#define NFEAT 4096   // WO*BLOCK
#define BM 128
#define BN 128
#define BK 64
#define LDA 72       // BK + 8 pad (bf16 elems) -> 144B stride, 2-way bank alias only

typedef __attribute__((ext_vector_type(8))) short short8;
typedef __attribute__((ext_vector_type(4))) float f32x4;

__device__ inline unsigned short f2bf(float f) {
    union { float f; unsigned u; } v; v.f = f;
    unsigned r = v.u + 0x7FFFu + ((v.u >> 16) & 1u);   // RNE
    return (unsigned short)(r >> 16);
}

// Phase-decomposed block-sparse GEMM:
// phase p handles out-block-rows ro = p + 4*A (A=0..31); all share in-block set
// ci[p*32 + b], b=0..31 (gathered K = 1024).
// grid = (M/BM, 1024/BN, 4 phases), 256 threads (4 waves, 2x2 wave grid, 64x64/wave)
__global__ __launch_bounds__(256) void bsmm_kernel(
    const float* __restrict__ x, const float* __restrict__ w,
    const int* __restrict__ ci, float* __restrict__ y)
{
    __shared__ unsigned short As[BM * LDA];
    __shared__ unsigned short Bs[BN * LDA];
    __shared__ int cis[32];

    const int p     = blockIdx.z;
    const int ntile = blockIdx.y;
    const int mbase = blockIdx.x * BM;
    const int t     = threadIdx.x;

    if (t < 32) cis[t] = ci[p * 32 + t];

    const int lane = t & 63;
    const int wv   = t >> 6;
    const int wm   = wv >> 1, wn = wv & 1;
    const int lr   = lane & 15;
    const int lk   = (lane >> 4) * 8;

    const int tr  = t >> 4;          // 0..15 (staging row-within-pass)
    const int tc4 = (t & 15) * 4;    // 0..60 (staging k-offset)
    const int hh  = tc4 >> 5;        // which of the 2 in-blocks in this k-step
    const int cc  = tc4 & 31;

    f32x4 acc[4][4];
    #pragma unroll
    for (int i = 0; i < 4; i++)
        #pragma unroll
        for (int j = 0; j < 4; j++)
            acc[i][j] = (f32x4){0.f, 0.f, 0.f, 0.f};

    __syncthreads();   // cis visible

    for (int ks = 0; ks < 16; ++ks) {
        const int b0 = ks * 2;
        const int fbase = cis[b0 + hh] * 32 + cc;   // gathered feature for A
        #pragma unroll
        for (int q = 0; q < 8; ++q) {
            const int row = q * 16 + tr;
            // --- A tile: x[mbase+row][fbase..+3], fp32 -> bf16
            const float4 va = *(const float4*)(x + (size_t)(mbase + row) * NFEAT + fbase);
            ushort4 ua; ua.x = f2bf(va.x); ua.y = f2bf(va.y); ua.z = f2bf(va.z); ua.w = f2bf(va.w);
            *(ushort4*)&As[row * LDA + tc4] = ua;
            // --- B tile (stored as Bt[n][k] = W[out_n, k]): w_blocks row-major is already [out][k]
            const int ablk = row >> 5, rr = row & 31;
            const int ro = p + 4 * (ntile * 4 + ablk);
            const int blkidx = ro * 32 + b0 + hh;   // nnz index (row-major sorted, 32/row)
            const float4 vb = *(const float4*)(w + (size_t)blkidx * 1024 + rr * 32 + cc);
            ushort4 ub; ub.x = f2bf(vb.x); ub.y = f2bf(vb.y); ub.z = f2bf(vb.z); ub.w = f2bf(vb.w);
            *(ushort4*)&Bs[row * LDA + tc4] = ub;
        }
        __syncthreads();

        #pragma unroll
        for (int kk = 0; kk < 2; ++kk) {
            short8 af[4], bf[4];
            #pragma unroll
            for (int i = 0; i < 4; i++)
                af[i] = *(const short8*)&As[(wm * 64 + i * 16 + lr) * LDA + kk * 32 + lk];
            #pragma unroll
            for (int j = 0; j < 4; j++)
                bf[j] = *(const short8*)&Bs[(wn * 64 + j * 16 + lr) * LDA + kk * 32 + lk];
            #pragma unroll
            for (int i = 0; i < 4; i++)
                #pragma unroll
                for (int j = 0; j < 4; j++)
                    acc[i][j] = __builtin_amdgcn_mfma_f32_16x16x32_bf16(af[i], bf[j], acc[i][j], 0, 0, 0);
        }
        __syncthreads();
    }

    // epilogue: D col = lane&15, row = (lane>>4)*4 + reg  [m89-verified mapping]
    #pragma unroll
    for (int i = 0; i < 4; i++) {
        #pragma unroll
        for (int q = 0; q < 4; q++) {
            const int row = mbase + wm * 64 + i * 16 + (lane >> 4) * 4 + q;
            float* yrow = y + (size_t)row * NFEAT;
            #pragma unroll
            for (int j = 0; j < 4; j++) {
                const int n = ntile * 128 + wn * 64 + j * 16 + lr;  // gathered out col
                const int A = n >> 5, rr = n & 31;
                const int feat = (p + 4 * A) * 32 + rr;             // real out feature
                yrow[feat] = acc[i][j][q];
            }
        }
    }
}

extern "C" void kernel_launch(void* const* d_in, const int* in_sizes, int n_in,
                              void* d_out, int out_size, void* d_ws, size_t ws_size,
                              hipStream_t stream) {
    const float* x  = (const float*)d_in[0];
    const float* w  = (const float*)d_in[1];
    const int*   ci = (const int*)d_in[3];
    float* y = (float*)d_out;
    dim3 grid(NTOK / BM, (HO / 4 * BLOCK) / BN, 4);
    dim3 blk(256);
    hipLaunchKernelGGL(bsmm_kernel, grid, blk, 0, stream, x, w, ci, y);
}

// Round 4
// 342.946 us; speedup vs baseline: 1.0423x; 1.0423x over previous
//
#include <hip/hip_runtime.h>
#include <hip/hip_bf16.h>

#define BLOCK 32
#define HO 128
#define WO 128
#define NTOK 8192
#define NFEAT 4096

typedef __attribute__((ext_vector_type(8))) short short8;
typedef __attribute__((ext_vector_type(4))) float f32x4;

__device__ inline unsigned short f2bf(float f) {
    union { float f; unsigned u; } v; v.f = f;
    unsigned r = v.u + 0x7FFFu + ((v.u >> 16) & 1u);   // RNE
    return (unsigned short)(r >> 16);
}

// ---------------- pass 1a: convert + column-gather x -> xg[4][8192][1024] bf16
// column-block cb belongs to phase p=(4-(cb&3))&3 at gathered position kb=cb>>2.
__global__ __launch_bounds__(256) void cvt_x(const float* __restrict__ x,
                                             unsigned short* __restrict__ xg) {
    const size_t f8 = ((size_t)blockIdx.x * 256 + threadIdx.x) * 8;
    const int m  = (int)(f8 >> 12);
    const int f  = (int)(f8 & 4095);
    const int cb = f >> 5;
    const int p  = (4 - (cb & 3)) & 3;
    const int dcol = ((cb >> 2) << 5) + (f & 31);
    const float4 v0 = *(const float4*)(x + f8);
    const float4 v1 = *(const float4*)(x + f8 + 4);
    short8 u;
    u[0] = (short)f2bf(v0.x); u[1] = (short)f2bf(v0.y);
    u[2] = (short)f2bf(v0.z); u[3] = (short)f2bf(v0.w);
    u[4] = (short)f2bf(v1.x); u[5] = (short)f2bf(v1.y);
    u[6] = (short)f2bf(v1.z); u[7] = (short)f2bf(v1.w);
    *(short8*)(xg + (size_t)p * NTOK * 1024 + (size_t)m * 1024 + dcol) = u;
}

// ---------------- pass 1b: convert + gather w -> wg[4][1024][1024] bf16 (n-major)
// nnz block bi = ro*32 + t (row-major LUT order, verified R1); ro = p + 4A.
// wg[p][A*32 + rr][t*32 + cc] = w[bi][rr][cc]
__global__ __launch_bounds__(256) void cvt_w(const float* __restrict__ w,
                                             unsigned short* __restrict__ wg) {
    const size_t f8 = ((size_t)blockIdx.x * 256 + threadIdx.x) * 8;
    const int bi = (int)(f8 >> 10);
    const int rr = (int)((f8 >> 5) & 31);
    const int cc = (int)(f8 & 31);
    const int ro = bi >> 5, tt = bi & 31;
    const int p  = ro & 3,  A  = ro >> 2;
    const float4 v0 = *(const float4*)(w + f8);
    const float4 v1 = *(const float4*)(w + f8 + 4);
    short8 u;
    u[0] = (short)f2bf(v0.x); u[1] = (short)f2bf(v0.y);
    u[2] = (short)f2bf(v0.z); u[3] = (short)f2bf(v0.w);
    u[4] = (short)f2bf(v1.x); u[5] = (short)f2bf(v1.y);
    u[6] = (short)f2bf(v1.z); u[7] = (short)f2bf(v1.w);
    *(short8*)(wg + (size_t)p * 1024 * 1024 + (size_t)(A * 32 + rr) * 1024
               + tt * 32 + cc) = u;
}

// ---------------- pass 2: dense bf16 GEMM per phase (m97 structure)
// y_gathered = xg[p] @ wg[p]^T ; scatter out-col n -> feat=(p+4*(n>>5))*32+(n&31)
__device__ inline void gld16(const unsigned short* g, unsigned short* l) {
    __builtin_amdgcn_global_load_lds(
        (const __attribute__((address_space(1))) unsigned int*)g,
        (__attribute__((address_space(3))) unsigned int*)l, 16, 0, 0);
}

__global__ __launch_bounds__(256) void gemm_kernel(
    const unsigned short* __restrict__ xg, const unsigned short* __restrict__ wg,
    float* __restrict__ y)
{
    __shared__ unsigned short As[128 * 64];   // linear, global_load_lds dest
    __shared__ unsigned short Bs[128 * 64];

    const int p     = blockIdx.z;
    const int mbase = blockIdx.x * 128;
    const int nbase = blockIdx.y * 128;
    const unsigned short* Ab = xg + (size_t)p * NTOK * 1024 + (size_t)mbase * 1024;
    const unsigned short* Bb = wg + (size_t)p * 1024 * 1024 + (size_t)nbase * 1024;

    const int t    = threadIdx.x;
    const int lane = t & 63;
    const int wv   = t >> 6;
    const int wm   = wv >> 1, wn = wv & 1;
    const int lr   = lane & 15;
    const int lk   = (lane >> 4) * 8;
    const int srow = t >> 3;            // staging: row within 32-row group
    const int scol = (t & 7) * 8;       // staging: bf16 col offset (16B chunks)

    f32x4 acc[4][4];
    #pragma unroll
    for (int i = 0; i < 4; i++)
        #pragma unroll
        for (int j = 0; j < 4; j++)
            acc[i][j] = (f32x4){0.f, 0.f, 0.f, 0.f};

    for (int ks = 0; ks < 16; ++ks) {
        const int k0 = ks * 64;
        #pragma unroll
        for (int c = 0; c < 4; ++c) {
            const int row = c * 32 + srow;
            gld16(Ab + (size_t)row * 1024 + k0 + scol, &As[row * 64 + scol]);
            gld16(Bb + (size_t)row * 1024 + k0 + scol, &Bs[row * 64 + scol]);
        }
        __syncthreads();   // drains vmcnt before barrier (compiler-emitted)

        #pragma unroll
        for (int kk = 0; kk < 2; ++kk) {
            short8 af[4], bf[4];
            #pragma unroll
            for (int i = 0; i < 4; i++)
                af[i] = *(const short8*)&As[(wm * 64 + i * 16 + lr) * 64 + kk * 32 + lk];
            #pragma unroll
            for (int j = 0; j < 4; j++)
                bf[j] = *(const short8*)&Bs[(wn * 64 + j * 16 + lr) * 64 + kk * 32 + lk];
            #pragma unroll
            for (int i = 0; i < 4; i++)
                #pragma unroll
                for (int j = 0; j < 4; j++)
                    acc[i][j] = __builtin_amdgcn_mfma_f32_16x16x32_bf16(af[i], bf[j], acc[i][j], 0, 0, 0);
        }
        __syncthreads();
    }

    // epilogue: D col = lane&15, row = (lane>>4)*4 + reg  [m89 mapping]
    #pragma unroll
    for (int i = 0; i < 4; i++) {
        #pragma unroll
        for (int q = 0; q < 4; q++) {
            const int row = mbase + wm * 64 + i * 16 + (lane >> 4) * 4 + q;
            float* yrow = y + (size_t)row * NFEAT;
            #pragma unroll
            for (int j = 0; j < 4; j++) {
                const int n = nbase + wn * 64 + j * 16 + lr;
                const int feat = (p + 4 * (n >> 5)) * 32 + (n & 31);
                yrow[feat] = acc[i][j][q];
            }
        }
    }
}

// ---------------- fallback (R1 fused kernel) if workspace too small ----------
#define LDA 72
__global__ __launch_bounds__(256) void bsmm_kernel(
    const float* __restrict__ x, const float* __restrict__ w,
    const int* __restrict__ ci, float* __restrict__ y)
{
    __shared__ unsigned short As[128 * LDA];
    __shared__ unsigned short Bs[128 * LDA];
    __shared__ int cis[32];
    const int p = blockIdx.z, ntile = blockIdx.y, mbase = blockIdx.x * 128;
    const int t = threadIdx.x;
    if (t < 32) cis[t] = ci[p * 32 + t];
    const int lane = t & 63, wv = t >> 6, wm = wv >> 1, wn = wv & 1;
    const int lr = lane & 15, lk = (lane >> 4) * 8;
    const int tr = t >> 4, tc4 = (t & 15) * 4, hh = tc4 >> 5, cc = tc4 & 31;
    f32x4 acc[4][4];
    #pragma unroll
    for (int i = 0; i < 4; i++)
        #pragma unroll
        for (int j = 0; j < 4; j++) acc[i][j] = (f32x4){0.f, 0.f, 0.f, 0.f};
    __syncthreads();
    for (int ks = 0; ks < 16; ++ks) {
        const int b0 = ks * 2;
        const int fbase = cis[b0 + hh] * 32 + cc;
        #pragma unroll
        for (int q = 0; q < 8; ++q) {
            const int row = q * 16 + tr;
            const float4 va = *(const float4*)(x + (size_t)(mbase + row) * NFEAT + fbase);
            ushort4 ua; ua.x = f2bf(va.x); ua.y = f2bf(va.y); ua.z = f2bf(va.z); ua.w = f2bf(va.w);
            *(ushort4*)&As[row * LDA + tc4] = ua;
            const int ablk = row >> 5, rr = row & 31;
            const int ro = p + 4 * (ntile * 4 + ablk);
            const int blkidx = ro * 32 + b0 + hh;
            const float4 vb = *(const float4*)(w + (size_t)blkidx * 1024 + rr * 32 + cc);
            ushort4 ub; ub.x = f2bf(vb.x); ub.y = f2bf(vb.y); ub.z = f2bf(vb.z); ub.w = f2bf(vb.w);
            *(ushort4*)&Bs[row * LDA + tc4] = ub;
        }
        __syncthreads();
        #pragma unroll
        for (int kk = 0; kk < 2; ++kk) {
            short8 af[4], bf[4];
            #pragma unroll
            for (int i = 0; i < 4; i++) af[i] = *(const short8*)&As[(wm * 64 + i * 16 + lr) * LDA + kk * 32 + lk];
            #pragma unroll
            for (int j = 0; j < 4; j++) bf[j] = *(const short8*)&Bs[(wn * 64 + j * 16 + lr) * LDA + kk * 32 + lk];
            #pragma unroll
            for (int i = 0; i < 4; i++)
                #pragma unroll
                for (int j = 0; j < 4; j++)
                    acc[i][j] = __builtin_amdgcn_mfma_f32_16x16x32_bf16(af[i], bf[j], acc[i][j], 0, 0, 0);
        }
        __syncthreads();
    }
    #pragma unroll
    for (int i = 0; i < 4; i++)
        #pragma unroll
        for (int q = 0; q < 4; q++) {
            const int row = mbase + wm * 64 + i * 16 + (lane >> 4) * 4 + q;
            float* yrow = y + (size_t)row * NFEAT;
            #pragma unroll
            for (int j = 0; j < 4; j++) {
                const int n = ntile * 128 + wn * 64 + j * 16 + lr;
                const int A = n >> 5, rr2 = n & 31;
                yrow[(p + 4 * A) * 32 + rr2] = acc[i][j][q];
            }
        }
}

extern "C" void kernel_launch(void* const* d_in, const int* in_sizes, int n_in,
                              void* d_out, int out_size, void* d_ws, size_t ws_size,
                              hipStream_t stream) {
    const float* x  = (const float*)d_in[0];
    const float* w  = (const float*)d_in[1];
    const int*   ci = (const int*)d_in[3];
    float* y = (float*)d_out;

    const size_t xg_elems = (size_t)4 * NTOK * 1024;      // 33.5M bf16
    const size_t wg_elems = (size_t)4 * 1024 * 1024;      // 4M bf16
    const size_t need = (xg_elems + wg_elems) * 2;        // ~72 MB

    if (ws_size >= need) {
        unsigned short* xg = (unsigned short*)d_ws;
        unsigned short* wg = xg + xg_elems;
        hipLaunchKernelGGL(cvt_x, dim3((NTOK * (size_t)NFEAT) / (256 * 8)), dim3(256),
                           0, stream, x, xg);
        hipLaunchKernelGGL(cvt_w, dim3((4096 * 1024) / (256 * 8)), dim3(256),
                           0, stream, w, wg);
        dim3 grid(NTOK / 128, 1024 / 128, 4);
        hipLaunchKernelGGL(gemm_kernel, grid, dim3(256), 0, stream, xg, wg, y);
    } else {
        dim3 grid(NTOK / 128, 8, 4);
        hipLaunchKernelGGL(bsmm_kernel, grid, dim3(256), 0, stream, x, w, ci, y);
    }
}

// Round 9
// 332.259 us; speedup vs baseline: 1.0758x; 1.0322x over previous
//
#include <hip/hip_runtime.h>
#include <hip/hip_bf16.h>

#define BLOCK 32
#define HO 128
#define WO 128
#define NTOK 8192
#define NFEAT 4096

typedef __attribute__((ext_vector_type(8))) short short8;
typedef __attribute__((ext_vector_type(4))) float f32x4;

__device__ inline unsigned short f2bf(float f) {
    union { float f; unsigned u; } v; v.f = f;
    unsigned r = v.u + 0x7FFFu + ((v.u >> 16) & 1u);   // RNE
    return (unsigned short)(r >> 16);
}

__device__ __forceinline__ void gld16(const unsigned short* g, unsigned short* l) {
    __builtin_amdgcn_global_load_lds(
        (const __attribute__((address_space(1))) unsigned int*)g,
        (__attribute__((address_space(3))) unsigned int*)l, 16, 0, 0);
}

#define VMCNT(N) asm volatile("s_waitcnt vmcnt(" #N ")" ::: "memory")
#define LGKM0 do { asm volatile("s_waitcnt lgkmcnt(0)" ::: "memory"); \
                   __builtin_amdgcn_sched_barrier(0); } while (0)
#define BAR() __builtin_amdgcn_s_barrier()

// ---------------- pass 1a: convert + gather + pre-swizzle x -> xg[4][8192][1024]
// dest-driven (coalesced writes). Swizzle: within each 64-elem K-tile group,
// col ^= (row&4)<<2  (st_16x32: byte bit9 -> bit5), matching GEMM ds_read XOR.
__global__ __launch_bounds__(256) void cvt_x(const float* __restrict__ x,
                                             unsigned short* __restrict__ xg) {
    const size_t d8 = ((size_t)blockIdx.x * 256 + threadIdx.x) * 8;
    const int p   = (int)(d8 >> 23);
    const int rem = (int)(d8 & ((1u << 23) - 1));
    const int m   = rem >> 10;
    const int dcs = rem & 1023;                       // swizzled dest col (8-aligned)
    const int c6  = (dcs & 63) ^ ((m & 4) << 2);      // unswizzled col within K-tile
    const int dcol = (dcs & ~63) | c6;
    const int kb = dcol >> 5;
    const int cb = (kb << 2) + ((4 - p) & 3);
    const int f  = (cb << 5) + (dcol & 31);           // 8 contiguous source floats
    const float* src = x + (size_t)m * NFEAT + f;
    const float4 v0 = *(const float4*)src;
    const float4 v1 = *(const float4*)(src + 4);
    short8 u;
    u[0] = (short)f2bf(v0.x); u[1] = (short)f2bf(v0.y);
    u[2] = (short)f2bf(v0.z); u[3] = (short)f2bf(v0.w);
    u[4] = (short)f2bf(v1.x); u[5] = (short)f2bf(v1.y);
    u[6] = (short)f2bf(v1.z); u[7] = (short)f2bf(v1.w);
    *(short8*)(xg + d8) = u;
}

// ---------------- pass 1b: convert + gather + pre-swizzle w -> wg[4][1024][1024]
__global__ __launch_bounds__(256) void cvt_w(const float* __restrict__ w,
                                             unsigned short* __restrict__ wg) {
    const size_t d8 = ((size_t)blockIdx.x * 256 + threadIdx.x) * 8;
    const int p   = (int)(d8 >> 20);
    const int rem = (int)(d8 & ((1u << 20) - 1));
    const int n   = rem >> 10;
    const int kcs = rem & 1023;
    const int k6  = (kcs & 63) ^ ((n & 4) << 2);
    const int kcol = (kcs & ~63) | k6;
    const int tt = kcol >> 5, cc = kcol & 31;
    const int ro = p + 4 * (n >> 5), rr = n & 31;
    const int bi = ro * 32 + tt;
    const float* src = w + (size_t)bi * 1024 + rr * 32 + cc;
    const float4 v0 = *(const float4*)src;
    const float4 v1 = *(const float4*)(src + 4);
    short8 u;
    u[0] = (short)f2bf(v0.x); u[1] = (short)f2bf(v0.y);
    u[2] = (short)f2bf(v0.z); u[3] = (short)f2bf(v0.w);
    u[4] = (short)f2bf(v1.x); u[5] = (short)f2bf(v1.y);
    u[6] = (short)f2bf(v1.z); u[7] = (short)f2bf(v1.w);
    *(short8*)(wg + d8) = u;
}

// ---------------- pass 2: 256x256 8-phase GEMM (T2+T3+T4+T5), per m201/m248
template<int QM>
__device__ __forceinline__ void load_a(short8 (&dst)[4][2], const unsigned short* s,
                                       int wm, int lr, int kb8, int csw) {
#pragma unroll
    for (int i = 0; i < 4; i++)
#pragma unroll
        for (int kk = 0; kk < 2; kk++)
            dst[i][kk] = *(const short8*)&s[(wm * 128 + QM * 64 + i * 16 + lr) * 64
                                            + ((kk * 32 + kb8) ^ csw)];
}
template<int QN>
__device__ __forceinline__ void load_b(short8 (&dst)[2][2], const unsigned short* s,
                                       int wn, int lr, int kb8, int csw) {
#pragma unroll
    for (int j = 0; j < 2; j++)
#pragma unroll
        for (int kk = 0; kk < 2; kk++)
            dst[j][kk] = *(const short8*)&s[(wn * 64 + QN * 32 + j * 16 + lr) * 64
                                            + ((kk * 32 + kb8) ^ csw)];
}
template<int QM, int QN>
__device__ __forceinline__ void mfma_quad(f32x4 (&acc)[8][4], const short8 (&a)[4][2],
                                          const short8 (&b)[2][2]) {
#pragma unroll
    for (int i = 0; i < 4; i++)
#pragma unroll
        for (int j = 0; j < 2; j++)
#pragma unroll
            for (int kk = 0; kk < 2; kk++)
                acc[QM * 4 + i][QN * 2 + j] = __builtin_amdgcn_mfma_f32_16x16x32_bf16(
                    a[i][kk], b[j][kk], acc[QM * 4 + i][QN * 2 + j], 0, 0, 0);
}

__device__ __forceinline__ void stage_half(const unsigned short* gbase,
                                           unsigned short* lbase,
                                           int hf, int tt, int sr, int sc) {
    const int r0 = hf * 128 + sr;
    gld16(gbase + (size_t)r0 * 1024 + tt * 64 + sc, lbase + r0 * 64 + sc);
    gld16(gbase + (size_t)(r0 + 8) * 1024 + tt * 64 + sc, lbase + (r0 + 8) * 64 + sc);
}

__global__ __launch_bounds__(512, 2) void gemm8(
    const unsigned short* __restrict__ xg, const unsigned short* __restrict__ wg,
    float* __restrict__ y)
{
    __shared__ unsigned short As[2][256 * 64];
    __shared__ unsigned short Bs[2][256 * 64];

    const int p     = blockIdx.z;
    const int mbase = blockIdx.x * 256;
    const int nbase = blockIdx.y * 256;
    const unsigned short* Ab = xg + (size_t)p * NTOK * 1024 + (size_t)mbase * 1024;
    const unsigned short* Bb = wg + (size_t)p * 1024 * 1024 + (size_t)nbase * 1024;

    const int t    = threadIdx.x;
    const int lane = t & 63;
    const int wv   = t >> 6;               // 0..7
    const int wm   = wv >> 2, wn = wv & 3; // 2 x 4 wave grid
    const int lr   = lane & 15;
    const int kb8  = (lane >> 4) * 8;
    const int csw  = (lr & 4) << 2;        // st_16x32 swizzle XOR (0 or 16)
    const int sr   = wv * 16 + (lane >> 3);// staging row within 128-half
    const int sc   = (lane & 7) * 8;       // staging col (bf16 elems)

    f32x4 acc[8][4];
#pragma unroll
    for (int i = 0; i < 8; i++)
#pragma unroll
        for (int j = 0; j < 4; j++)
            acc[i][j] = (f32x4){0.f, 0.f, 0.f, 0.f};

    short8 a0[4][2], a1[4][2], b0[2][2], b1[2][2];

    // prologue: tile0 -> buf0 (4 halves), tile1 A-h0 -> buf1
    stage_half(Ab, &As[0][0], 0, 0, sr, sc);
    stage_half(Ab, &As[0][0], 1, 0, sr, sc);
    stage_half(Bb, &Bs[0][0], 0, 0, sr, sc);
    stage_half(Bb, &Bs[0][0], 1, 0, sr, sc);
    stage_half(Ab, &As[1][0], 0, 1, sr, sc);
    VMCNT(2);
    BAR();

    for (int it = 0; it < 8; ++it) {
        const int t1 = 2 * it + 1;
        const int t2 = 2 * it + 2;
        const int t3 = 2 * it + 3;
        const bool more = (it < 7);

        // ph1: read A-q0 + B-q0 (buf0); stage t1 A-h1 -> buf1
        load_a<0>(a0, &As[0][0], wm, lr, kb8, csw);
        load_b<0>(b0, &Bs[0][0], wn, lr, kb8, csw);
        stage_half(Ab, &As[1][0], 1, t1, sr, sc);
        BAR(); LGKM0;
        __builtin_amdgcn_s_setprio(1); mfma_quad<0, 0>(acc, a0, b0); __builtin_amdgcn_s_setprio(0);
        BAR();

        // ph2: read A-q1 (buf0); stage t1 B-h0 -> buf1
        load_a<1>(a1, &As[0][0], wm, lr, kb8, csw);
        stage_half(Bb, &Bs[1][0], 0, t1, sr, sc);
        BAR(); LGKM0;
        __builtin_amdgcn_s_setprio(1); mfma_quad<1, 0>(acc, a1, b0); __builtin_amdgcn_s_setprio(0);
        BAR();

        // ph3: read B-q1 (buf0); stage t1 B-h1 -> buf1
        load_b<1>(b1, &Bs[0][0], wn, lr, kb8, csw);
        stage_half(Bb, &Bs[1][0], 1, t1, sr, sc);
        BAR(); LGKM0;
        __builtin_amdgcn_s_setprio(1); mfma_quad<0, 1>(acc, a0, b1); __builtin_amdgcn_s_setprio(0);
        BAR();

        // ph4: stage t2 A-h0 -> buf0; q(1,1); vmcnt checkpoint (protects ph5 reads)
        if (more) stage_half(Ab, &As[0][0], 0, t2, sr, sc);
        BAR();
        __builtin_amdgcn_s_setprio(1); mfma_quad<1, 1>(acc, a1, b1); __builtin_amdgcn_s_setprio(0);
        if (more) VMCNT(2); else VMCNT(0);
        BAR();

        // ph5: read A-q0 + B-q0 (buf1); stage t2 A-h1 -> buf0
        load_a<0>(a0, &As[1][0], wm, lr, kb8, csw);
        load_b<0>(b0, &Bs[1][0], wn, lr, kb8, csw);
        if (more) stage_half(Ab, &As[0][0], 1, t2, sr, sc);
        BAR(); LGKM0;
        __builtin_amdgcn_s_setprio(1); mfma_quad<0, 0>(acc, a0, b0); __builtin_amdgcn_s_setprio(0);
        BAR();

        // ph6: read A-q1 (buf1); stage t2 B-h0 -> buf0
        load_a<1>(a1, &As[1][0], wm, lr, kb8, csw);
        if (more) stage_half(Bb, &Bs[0][0], 0, t2, sr, sc);
        BAR(); LGKM0;
        __builtin_amdgcn_s_setprio(1); mfma_quad<1, 0>(acc, a1, b0); __builtin_amdgcn_s_setprio(0);
        BAR();

        // ph7: read B-q1 (buf1); stage t2 B-h1 -> buf0
        load_b<1>(b1, &Bs[1][0], wn, lr, kb8, csw);
        if (more) stage_half(Bb, &Bs[0][0], 1, t2, sr, sc);
        BAR(); LGKM0;
        __builtin_amdgcn_s_setprio(1); mfma_quad<0, 1>(acc, a0, b1); __builtin_amdgcn_s_setprio(0);
        BAR();

        // ph8: stage t3 A-h0 -> buf1; q(1,1); vmcnt checkpoint (protects next ph1)
        if (more) stage_half(Ab, &As[1][0], 0, t3, sr, sc);
        BAR();
        __builtin_amdgcn_s_setprio(1); mfma_quad<1, 1>(acc, a1, b1); __builtin_amdgcn_s_setprio(0);
        if (more) VMCNT(2);
        BAR();
    }

    // epilogue: D col = lane&15, row = (lane>>4)*4 + reg  [m89 mapping]
#pragma unroll
    for (int i = 0; i < 8; i++) {
#pragma unroll
        for (int q = 0; q < 4; q++) {
            const int row = mbase + wm * 128 + i * 16 + (lane >> 4) * 4 + q;
            float* yrow = y + (size_t)row * NFEAT;
#pragma unroll
            for (int j = 0; j < 4; j++) {
                const int n = nbase + wn * 64 + j * 16 + lr;
                const int feat = (p + 4 * (n >> 5)) * 32 + (n & 31);
                yrow[feat] = acc[i][j][q];
            }
        }
    }
}

// ---------------- fallback (R1 fused kernel) if workspace too small ----------
#define LDA 72
__global__ __launch_bounds__(256) void bsmm_kernel(
    const float* __restrict__ x, const float* __restrict__ w,
    const int* __restrict__ ci, float* __restrict__ y)
{
    __shared__ unsigned short As[128 * LDA];
    __shared__ unsigned short Bs[128 * LDA];
    __shared__ int cis[32];
    const int p = blockIdx.z, ntile = blockIdx.y, mbase = blockIdx.x * 128;
    const int t = threadIdx.x;
    if (t < 32) cis[t] = ci[p * 32 + t];
    const int lane = t & 63, wv = t >> 6, wm = wv >> 1, wn = wv & 1;
    const int lr = lane & 15, lk = (lane >> 4) * 8;
    const int tr = t >> 4, tc4 = (t & 15) * 4, hh = tc4 >> 5, cc = tc4 & 31;
    f32x4 acc[4][4];
#pragma unroll
    for (int i = 0; i < 4; i++)
#pragma unroll
        for (int j = 0; j < 4; j++) acc[i][j] = (f32x4){0.f, 0.f, 0.f, 0.f};
    __syncthreads();
    for (int ks = 0; ks < 16; ++ks) {
        const int b0 = ks * 2;
        const int fbase = cis[b0 + hh] * 32 + cc;
#pragma unroll
        for (int q = 0; q < 8; ++q) {
            const int row = q * 16 + tr;
            const float4 va = *(const float4*)(x + (size_t)(mbase + row) * NFEAT + fbase);
            ushort4 ua; ua.x = f2bf(va.x); ua.y = f2bf(va.y); ua.z = f2bf(va.z); ua.w = f2bf(va.w);
            *(ushort4*)&As[row * LDA + tc4] = ua;
            const int ablk = row >> 5, rr = row & 31;
            const int ro = p + 4 * (ntile * 4 + ablk);
            const int blkidx = ro * 32 + b0 + hh;
            const float4 vb = *(const float4*)(w + (size_t)blkidx * 1024 + rr * 32 + cc);
            ushort4 ub; ub.x = f2bf(vb.x); ub.y = f2bf(vb.y); ub.z = f2bf(vb.z); ub.w = f2bf(vb.w);
            *(ushort4*)&Bs[row * LDA + tc4] = ub;
        }
        __syncthreads();
#pragma unroll
        for (int kk = 0; kk < 2; ++kk) {
            short8 af[4], bf[4];
#pragma unroll
            for (int i = 0; i < 4; i++) af[i] = *(const short8*)&As[(wm * 64 + i * 16 + lr) * LDA + kk * 32 + lk];
#pragma unroll
            for (int j = 0; j < 4; j++) bf[j] = *(const short8*)&Bs[(wn * 64 + j * 16 + lr) * LDA + kk * 32 + lk];
#pragma unroll
            for (int i = 0; i < 4; i++)
#pragma unroll
                for (int j = 0; j < 4; j++)
                    acc[i][j] = __builtin_amdgcn_mfma_f32_16x16x32_bf16(af[i], bf[j], acc[i][j], 0, 0, 0);
        }
        __syncthreads();
    }
#pragma unroll
    for (int i = 0; i < 4; i++)
#pragma unroll
        for (int q = 0; q < 4; q++) {
            const int row = mbase + wm * 64 + i * 16 + (lane >> 4) * 4 + q;
            float* yrow = y + (size_t)row * NFEAT;
#pragma unroll
            for (int j = 0; j < 4; j++) {
                const int n = ntile * 128 + wn * 64 + j * 16 + lr;
                const int A = n >> 5, rr2 = n & 31;
                yrow[(p + 4 * A) * 32 + rr2] = acc[i][j][q];
            }
        }
}

extern "C" void kernel_launch(void* const* d_in, const int* in_sizes, int n_in,
                              void* d_out, int out_size, void* d_ws, size_t ws_size,
                              hipStream_t stream) {
    const float* x  = (const float*)d_in[0];
    const float* w  = (const float*)d_in[1];
    const int*   ci = (const int*)d_in[3];
    float* y = (float*)d_out;

    const size_t xg_elems = (size_t)4 * NTOK * 1024;
    const size_t wg_elems = (size_t)4 * 1024 * 1024;
    const size_t need = (xg_elems + wg_elems) * 2;

    if (ws_size >= need) {
        unsigned short* xg = (unsigned short*)d_ws;
        unsigned short* wg = xg + xg_elems;
        hipLaunchKernelGGL(cvt_x, dim3(((size_t)4 * NTOK * 1024) / (256 * 8)), dim3(256),
                           0, stream, x, xg);
        hipLaunchKernelGGL(cvt_w, dim3(((size_t)4 * 1024 * 1024) / (256 * 8)), dim3(256),
                           0, stream, w, wg);
        dim3 grid(NTOK / 256, 1024 / 256, 4);
        hipLaunchKernelGGL(gemm8, grid, dim3(512), 0, stream, xg, wg, y);
    } else {
        dim3 grid(NTOK / 128, 8, 4);
        hipLaunchKernelGGL(bsmm_kernel, grid, dim3(256), 0, stream, x, w, ci, y);
    }
}